// Round 6
// baseline (558.666 us; speedup 1.0000x reference)
//
#include <hip/hip_runtime.h>
#include <hip/hip_bf16.h>

#define BB 8
#define SS 1024
#define DM 512
#define HH 8

typedef __bf16 bf16x8 __attribute__((ext_vector_type(8)));
typedef __bf16 bf16x4 __attribute__((ext_vector_type(4)));
typedef float f32x4 __attribute__((ext_vector_type(4)));

__device__ __forceinline__ f32x4 mfma16(bf16x8 a, bf16x8 b, f32x4 c) {
    return __builtin_amdgcn_mfma_f32_16x16x32_bf16(a, b, c, 0, 0, 0);
}

// ---------------- W transpose + hi/lo split ----------------
__global__ __launch_bounds__(256) void wconv(
    const float* __restrict__ W0, const float* __restrict__ W1,
    const float* __restrict__ W2, const float* __restrict__ W3,
    __bf16* __restrict__ th, __bf16* __restrict__ tl)
{
    const float* W = blockIdx.z == 0 ? W0 : blockIdx.z == 1 ? W1
                   : blockIdx.z == 2 ? W2 : W3;
    __bf16* oh = th + (size_t)blockIdx.z * 512 * 512;
    __bf16* ol = tl + (size_t)blockIdx.z * 512 * 512;
    __shared__ float T[64][65];
    const int k0 = blockIdx.x * 64, n0 = blockIdx.y * 64;
    const int r = threadIdx.x >> 4, c4 = (threadIdx.x & 15) * 4;
    #pragma unroll
    for (int p = 0; p < 4; ++p) {
        float4 v = *(const float4*)(W + (size_t)(k0 + p * 16 + r) * 512 + n0 + c4);
        T[p * 16 + r][c4 + 0] = v.x; T[p * 16 + r][c4 + 1] = v.y;
        T[p * 16 + r][c4 + 2] = v.z; T[p * 16 + r][c4 + 3] = v.w;
    }
    __syncthreads();
    #pragma unroll
    for (int p = 0; p < 4; ++p) {
        int n = n0 + p * 16 + r;
        bf16x4 h4, l4;
        #pragma unroll
        for (int j = 0; j < 4; ++j) {
            float x = T[c4 + j][p * 16 + r];
            __bf16 h = (__bf16)x;
            h4[j] = h; l4[j] = (__bf16)(x - (float)h);
        }
        *(bf16x4*)(oh + (size_t)n * 512 + k0 + c4) = h4;
        *(bf16x4*)(ol + (size_t)n * 512 + k0 + c4) = l4;
    }
}

// ---------------- Fused QKV projection GEMM ----------------
// grid (24, 128): z = bx>>3 (0=Q,1=K,2=V), nl = (bx&7)*64, m0 = by*64.
// NOTE: input A selected by z (this was the round-5 bug: all three used q).
__global__ __launch_bounds__(256, 4) void gemm_qkv(
    const float* __restrict__ Aq, const float* __restrict__ Ak,
    const float* __restrict__ Av,
    const __bf16* __restrict__ Wth, const __bf16* __restrict__ Wtl,
    const float* __restrict__ bq, const float* __restrict__ bk,
    const float* __restrict__ bv,
    __bf16* __restrict__ qo, __bf16* __restrict__ ko, __bf16* __restrict__ vo)
{
    const int tid = threadIdx.x;
    const int w = tid >> 6, lane = tid & 63, l15 = lane & 15, lg = lane >> 4;
    const int z = blockIdx.x >> 3;
    const int nl = (blockIdx.x & 7) * 64;
    const int m0 = blockIdx.y * 64;
    const int mrow = m0 + w * 16 + l15;
    const float* A = z == 0 ? Aq : z == 1 ? Ak : Av;
    const __bf16* wp = Wth + (size_t)z * 512 * 512 + (size_t)(nl + l15) * 512 + lg * 8;
    const __bf16* wl = Wtl + (size_t)z * 512 * 512 + (size_t)(nl + l15) * 512 + lg * 8;
    f32x4 acc[4] = {};

    #pragma unroll 2
    for (int k0 = 0; k0 < 512; k0 += 32) {
        const float* ap = A + (size_t)mrow * 512 + k0 + lg * 8;
        f32x4 a0 = *(const f32x4*)ap;
        f32x4 a1 = *(const f32x4*)(ap + 4);
        bf16x8 ah, al;
        #pragma unroll
        for (int j = 0; j < 4; ++j) {
            __bf16 h = (__bf16)a0[j]; ah[j] = h; al[j] = (__bf16)(a0[j] - (float)h);
        }
        #pragma unroll
        for (int j = 0; j < 4; ++j) {
            __bf16 h = (__bf16)a1[j]; ah[4 + j] = h; al[4 + j] = (__bf16)(a1[j] - (float)h);
        }
        #pragma unroll
        for (int nt = 0; nt < 4; ++nt) {
            bf16x8 bh = *(const bf16x8*)(wp + (size_t)nt * 16 * 512 + k0);
            bf16x8 bl = *(const bf16x8*)(wl + (size_t)nt * 16 * 512 + k0);
            acc[nt] = mfma16(ah, bh, acc[nt]);
            acc[nt] = mfma16(al, bh, acc[nt]);
            acc[nt] = mfma16(ah, bl, acc[nt]);
        }
    }

    const float* bias = z == 0 ? bq : z == 1 ? bk : bv;
    __bf16* outp = z == 0 ? qo : z == 1 ? ko : vo;
    #pragma unroll
    for (int nt = 0; nt < 4; ++nt) {
        int n = nl + nt * 16 + l15;
        float bz = bias[n];
        #pragma unroll
        for (int rr = 0; rr < 4; ++rr) {
            int m = m0 + w * 16 + lg * 4 + rr;
            float v = acc[nt][rr] + bz;
            int bb = m >> 10, s = m & 1023, h = n >> 6, d = n & 63;
            if (z < 2)
                outp[((size_t)(bb * HH + h) * SS + s) * 64 + d] = (__bf16)v;
            else
                outp[((size_t)(bb * HH + h) * 64 + d) * SS + s] = (__bf16)v;
        }
    }
}

// ---------------- final GEMM: out = ctx(hi/lo) @ Wo + bo ----------------
__global__ __launch_bounds__(256, 4) void gemm_out(
    const __bf16* __restrict__ Ahi, const __bf16* __restrict__ Alo,
    const __bf16* __restrict__ Wth, const __bf16* __restrict__ Wtl,
    const float* __restrict__ bias, float* __restrict__ Cf)
{
    const int tid = threadIdx.x;
    const int w = tid >> 6, lane = tid & 63, l15 = lane & 15, lg = lane >> 4;
    const int n0 = blockIdx.x * 64, m0 = blockIdx.y * 64;
    const int mrow = m0 + w * 16 + l15;
    f32x4 acc[4] = {};
    const __bf16* wp = Wth + (size_t)(n0 + l15) * 512 + lg * 8;
    const __bf16* wl = Wtl + (size_t)(n0 + l15) * 512 + lg * 8;

    #pragma unroll 2
    for (int k0 = 0; k0 < 512; k0 += 32) {
        bf16x8 ah = *(const bf16x8*)(Ahi + (size_t)mrow * 512 + k0 + lg * 8);
        bf16x8 al = *(const bf16x8*)(Alo + (size_t)mrow * 512 + k0 + lg * 8);
        #pragma unroll
        for (int nt = 0; nt < 4; ++nt) {
            bf16x8 bh = *(const bf16x8*)(wp + (size_t)nt * 16 * 512 + k0);
            bf16x8 bl = *(const bf16x8*)(wl + (size_t)nt * 16 * 512 + k0);
            acc[nt] = mfma16(ah, bh, acc[nt]);
            acc[nt] = mfma16(al, bh, acc[nt]);
            acc[nt] = mfma16(ah, bl, acc[nt]);
        }
    }
    #pragma unroll
    for (int nt = 0; nt < 4; ++nt) {
        int n = n0 + nt * 16 + l15;
        float bz = bias[n];
        #pragma unroll
        for (int rr = 0; rr < 4; ++rr) {
            int m = m0 + w * 16 + lg * 4 + rr;
            Cf[(size_t)m * 512 + n] = acc[nt][rr] + bz;
        }
    }
}

// ---------------- Fused attention: single QK pass, P~ in registers ----------------
// grid flat 512: qt = id>>3, b = id&7. 512 thr = 8 waves = 8 heads.
__global__ __launch_bounds__(512, 2) void attn3(
    const __bf16* __restrict__ qh, const __bf16* __restrict__ kh,
    const __bf16* __restrict__ vt,
    const float* __restrict__ mask, const float* __restrict__ adj,
    const float* __restrict__ dist,
    float* __restrict__ attn_out, __bf16* __restrict__ chi, __bf16* __restrict__ clo)
{
    __shared__ float nmb[1024];                    // (nm - 16) * log2e
    __shared__ __align__(16) __bf16 G[16][1028];   // adj * exp(dist+nm-1)
    __shared__ __align__(16) __bf16 Pch[8][16][40];
    __shared__ float rowIL[16];

    const int tid = threadIdx.x;
    const int w = tid >> 6, lane = tid & 63, l15 = lane & 15, lg = lane >> 4;
    const int q0 = (blockIdx.x >> 3) * 16;
    const int b = blockIdx.x & 7;
    const float L2E = 1.44269504f;

    #pragma unroll
    for (int i = 0; i < 2; ++i) {
        int c = tid + 512 * i;
        nmb[c] = fmaf(mask[(size_t)b * SS + c], -1e9f * L2E, -16.0f * L2E);
    }
    __syncthreads();

    // ---- G = adj * exp(dist + nm - 1); rowIL = 1/sum(exp(dist+nm-1)) ----
    {
        const int row = 2 * w + (lg >> 1);
        const int kb = (lg & 1) * 512;
        const size_t drow = ((size_t)b * SS + q0 + row) * SS;
        float sm = 0.f;
        #pragma unroll
        for (int j = 0; j < 8; ++j) {
            int c = kb + l15 * 4 + j * 64;
            f32x4 d4 = *(const f32x4*)(dist + drow + c);
            f32x4 a4 = *(const f32x4*)(adj + drow + c);
            f32x4 n4 = *(const f32x4*)&nmb[c];
            bf16x4 g4;
            #pragma unroll
            for (int r = 0; r < 4; ++r) {
                float e = exp2f(fmaf(d4[r], L2E, n4[r] + 15.0f * L2E));
                sm += e;
                g4[r] = (__bf16)(a4[r] * e);
            }
            *(bf16x4*)&G[row][c] = g4;
        }
        #pragma unroll
        for (int off = 1; off <= 16; off <<= 1)
            sm += __shfl_xor(sm, off, 64);
        if ((lane & 31) == 0) rowIL[row] = 1.0f / sm;
    }
    __syncthreads();

    // ---- per-wave head = w ----
    const size_t hb = ((size_t)(b * HH + w)) * SS * 64;
    bf16x8 qf[2];
    #pragma unroll
    for (int ks = 0; ks < 2; ++ks)
        qf[ks] = *(const bf16x8*)(qh + hb + (size_t)(q0 + l15) * 64 + ks * 32 + lg * 8);
    const float c1 = 0.125f * L2E;
    const __bf16* kp = kh + hb + (size_t)l15 * 64 + lg * 8;

    // single QK pass: P~ = e * G stored bf16 in regs; l = sum(e)
    bf16x4 pst[64];
    float lac0 = 0.f, lac1 = 0.f, lac2 = 0.f, lac3 = 0.f;
    bf16x8 ka = *(const bf16x8*)(kp);
    bf16x8 kb2 = *(const bf16x8*)(kp + 32);
    #pragma unroll
    for (int nt = 0; nt < 64; ++nt) {
        bf16x8 k0v = ka, k1v = kb2;
        if (nt < 63) {
            ka  = *(const bf16x8*)(kp + (size_t)(nt + 1) * 1024);
            kb2 = *(const bf16x8*)(kp + (size_t)(nt + 1) * 1024 + 32);
        }
        f32x4 acc = {0.f, 0.f, 0.f, 0.f};
        acc = mfma16(k0v, qf[0], acc);
        acc = mfma16(k1v, qf[1], acc);
        f32x4 nb4 = *(const f32x4*)&nmb[nt * 16 + lg * 4];
        bf16x4 g4 = *(const bf16x4*)&G[l15][nt * 16 + lg * 4];
        float e0 = exp2f(fmaf(acc[0], c1, nb4[0]));
        float e1 = exp2f(fmaf(acc[1], c1, nb4[1]));
        float e2 = exp2f(fmaf(acc[2], c1, nb4[2]));
        float e3 = exp2f(fmaf(acc[3], c1, nb4[3]));
        lac0 += e0; lac1 += e1; lac2 += e2; lac3 += e3;
        bf16x4 pb;
        pb[0] = (__bf16)(e0 * (float)g4[0]);
        pb[1] = (__bf16)(e1 * (float)g4[1]);
        pb[2] = (__bf16)(e2 * (float)g4[2]);
        pb[3] = (__bf16)(e3 * (float)g4[3]);
        pst[nt] = pb;
    }
    float l = (lac0 + lac1) + (lac2 + lac3);
    #pragma unroll
    for (int off = 16; off <= 32; off <<= 1)
        l += __shfl_xor(l, off, 64);
    const float coef = (1.0f / l) * rowIL[l15];

    // pass 2: attn write (P~ * coef) + PV (unnormalized, scale in epilogue)
    f32x4 cacc[4];
    #pragma unroll
    for (int dt = 0; dt < 4; ++dt) cacc[dt] = (f32x4){0.f, 0.f, 0.f, 0.f};
    float* aout = attn_out + ((size_t)(b * HH + w)) * SS * SS + (size_t)(q0 + l15) * SS;
    const __bf16* vb = vt + ((size_t)(b * HH + w) * 64 + l15) * SS + lg * 8;

    #pragma unroll
    for (int c = 0; c < 32; ++c) {
        #pragma unroll
        for (int t = 0; t < 2; ++t) {
            int nt = c * 2 + t;
            bf16x4 pb = pst[nt];
            f32x4 av;
            #pragma unroll
            for (int r = 0; r < 4; ++r) av[r] = (float)pb[r] * coef;
            __builtin_nontemporal_store(av, (f32x4*)(aout + nt * 16 + lg * 4));
            *(bf16x4*)&Pch[w][l15][t * 16 + lg * 4] = pb;
        }
        bf16x8 pa = *(const bf16x8*)&Pch[w][l15][lg * 8];
        #pragma unroll
        for (int dt = 0; dt < 4; ++dt)
            cacc[dt] = mfma16(pa, *(const bf16x8*)(vb + (size_t)(dt * 16) * SS + c * 32),
                              cacc[dt]);
    }

    // epilogue: scale by per-row coef, write ctx hi/lo
    float cq[4];
    #pragma unroll
    for (int r = 0; r < 4; ++r) cq[r] = __shfl(coef, lg * 4 + r, 16);
    #pragma unroll
    for (int dt = 0; dt < 4; ++dt)
        #pragma unroll
        for (int r = 0; r < 4; ++r) {
            float x = cacc[dt][r] * cq[r];
            __bf16 hv = (__bf16)x;
            size_t idx = ((size_t)b * SS + q0 + lg * 4 + r) * DM + w * 64 + dt * 16 + l15;
            chi[idx] = hv;
            clo[idx] = (__bf16)(x - (float)hv);
        }
}

extern "C" void kernel_launch(void* const* d_in, const int* in_sizes, int n_in,
                              void* d_out, int out_size, void* d_ws, size_t ws_size,
                              hipStream_t stream) {
    const float* q    = (const float*)d_in[0];
    const float* k    = (const float*)d_in[1];
    const float* v    = (const float*)d_in[2];
    const float* mask = (const float*)d_in[3];
    const float* adj  = (const float*)d_in[4];
    const float* dist = (const float*)d_in[5];
    const float* Wq   = (const float*)d_in[6];
    const float* bq   = (const float*)d_in[7];
    const float* Wk   = (const float*)d_in[8];
    const float* bk   = (const float*)d_in[9];
    const float* Wv   = (const float*)d_in[10];
    const float* bv   = (const float*)d_in[11];
    const float* Wo   = (const float*)d_in[12];
    const float* bo   = (const float*)d_in[13];

    const size_t NT = (size_t)BB * SS * DM;   // 4,194,304
    const size_t WN = 512 * 512;
    __bf16* wth = (__bf16*)d_ws;
    __bf16* wtl = wth + 4 * WN;
    __bf16* qhb = wtl + 4 * WN;
    __bf16* khb = qhb + NT;
    __bf16* vtb = khb + NT;
    __bf16* chi = vtb + NT;
    __bf16* clo = chi + NT;

    float* outp = (float*)d_out;
    float* attn = outp + NT;

    wconv<<<dim3(8, 8, 4), 256, 0, stream>>>(Wq, Wk, Wv, Wo, wth, wtl);

    gemm_qkv<<<dim3(24, 128), 256, 0, stream>>>(q, k, v, wth, wtl, bq, bk, bv, qhb, khb, vtb);

    attn3<<<512, 512, 0, stream>>>(qhb, khb, vtb, mask, adj, dist, attn, chi, clo);

    gemm_out<<<dim3(8, 128), 256, 0, stream>>>(chi, clo, wth + 3 * WN, wtl + 3 * WN, bo, outp);
}

// Round 8
// 489.186 us; speedup vs baseline: 1.1420x; 1.1420x over previous
//
#include <hip/hip_runtime.h>
#include <hip/hip_bf16.h>

#define BB 8
#define SS 1024
#define DM 512
#define HH 8

typedef __bf16 bf16x8 __attribute__((ext_vector_type(8)));
typedef __bf16 bf16x4 __attribute__((ext_vector_type(4)));
typedef float f32x4 __attribute__((ext_vector_type(4)));

__device__ __forceinline__ f32x4 mfma16(bf16x8 a, bf16x8 b, f32x4 c) {
    return __builtin_amdgcn_mfma_f32_16x16x32_bf16(a, b, c, 0, 0, 0);
}

// ---------------- W transpose + hi/lo split ----------------
__global__ __launch_bounds__(256) void wconv(
    const float* __restrict__ W0, const float* __restrict__ W1,
    const float* __restrict__ W2, const float* __restrict__ W3,
    __bf16* __restrict__ th, __bf16* __restrict__ tl)
{
    const float* W = blockIdx.z == 0 ? W0 : blockIdx.z == 1 ? W1
                   : blockIdx.z == 2 ? W2 : W3;
    __bf16* oh = th + (size_t)blockIdx.z * 512 * 512;
    __bf16* ol = tl + (size_t)blockIdx.z * 512 * 512;
    __shared__ float T[64][65];
    const int k0 = blockIdx.x * 64, n0 = blockIdx.y * 64;
    const int r = threadIdx.x >> 4, c4 = (threadIdx.x & 15) * 4;
    #pragma unroll
    for (int p = 0; p < 4; ++p) {
        float4 v = *(const float4*)(W + (size_t)(k0 + p * 16 + r) * 512 + n0 + c4);
        T[p * 16 + r][c4 + 0] = v.x; T[p * 16 + r][c4 + 1] = v.y;
        T[p * 16 + r][c4 + 2] = v.z; T[p * 16 + r][c4 + 3] = v.w;
    }
    __syncthreads();
    #pragma unroll
    for (int p = 0; p < 4; ++p) {
        int n = n0 + p * 16 + r;
        bf16x4 h4, l4;
        #pragma unroll
        for (int j = 0; j < 4; ++j) {
            float x = T[c4 + j][p * 16 + r];
            __bf16 h = (__bf16)x;
            h4[j] = h; l4[j] = (__bf16)(x - (float)h);
        }
        *(bf16x4*)(oh + (size_t)n * 512 + k0 + c4) = h4;
        *(bf16x4*)(ol + (size_t)n * 512 + k0 + c4) = l4;
    }
}

// ---------------- Fused QKV projection GEMM ----------------
__global__ __launch_bounds__(256, 4) void gemm_qkv(
    const float* __restrict__ Aq, const float* __restrict__ Ak,
    const float* __restrict__ Av,
    const __bf16* __restrict__ Wth, const __bf16* __restrict__ Wtl,
    const float* __restrict__ bq, const float* __restrict__ bk,
    const float* __restrict__ bv,
    __bf16* __restrict__ qo, __bf16* __restrict__ ko, __bf16* __restrict__ vo)
{
    const int tid = threadIdx.x;
    const int w = tid >> 6, lane = tid & 63, l15 = lane & 15, lg = lane >> 4;
    const int z = blockIdx.x >> 3;
    const int nl = (blockIdx.x & 7) * 64;
    const int m0 = blockIdx.y * 64;
    const int mrow = m0 + w * 16 + l15;
    const float* A = z == 0 ? Aq : z == 1 ? Ak : Av;
    const __bf16* wp = Wth + (size_t)z * 512 * 512 + (size_t)(nl + l15) * 512 + lg * 8;
    const __bf16* wl = Wtl + (size_t)z * 512 * 512 + (size_t)(nl + l15) * 512 + lg * 8;
    f32x4 acc[4] = {};

    #pragma unroll 2
    for (int k0 = 0; k0 < 512; k0 += 32) {
        const float* ap = A + (size_t)mrow * 512 + k0 + lg * 8;
        f32x4 a0 = *(const f32x4*)ap;
        f32x4 a1 = *(const f32x4*)(ap + 4);
        bf16x8 ah, al;
        #pragma unroll
        for (int j = 0; j < 4; ++j) {
            __bf16 h = (__bf16)a0[j]; ah[j] = h; al[j] = (__bf16)(a0[j] - (float)h);
        }
        #pragma unroll
        for (int j = 0; j < 4; ++j) {
            __bf16 h = (__bf16)a1[j]; ah[4 + j] = h; al[4 + j] = (__bf16)(a1[j] - (float)h);
        }
        #pragma unroll
        for (int nt = 0; nt < 4; ++nt) {
            bf16x8 bh = *(const bf16x8*)(wp + (size_t)nt * 16 * 512 + k0);
            bf16x8 bl = *(const bf16x8*)(wl + (size_t)nt * 16 * 512 + k0);
            acc[nt] = mfma16(ah, bh, acc[nt]);
            acc[nt] = mfma16(al, bh, acc[nt]);
            acc[nt] = mfma16(ah, bl, acc[nt]);
        }
    }

    const float* bias = z == 0 ? bq : z == 1 ? bk : bv;
    __bf16* outp = z == 0 ? qo : z == 1 ? ko : vo;
    #pragma unroll
    for (int nt = 0; nt < 4; ++nt) {
        int n = nl + nt * 16 + l15;
        float bz = bias[n];
        #pragma unroll
        for (int rr = 0; rr < 4; ++rr) {
            int m = m0 + w * 16 + lg * 4 + rr;
            float v = acc[nt][rr] + bz;
            int bb = m >> 10, s = m & 1023, h = n >> 6, d = n & 63;
            if (z < 2)
                outp[((size_t)(bb * HH + h) * SS + s) * 64 + d] = (__bf16)v;
            else
                outp[((size_t)(bb * HH + h) * 64 + d) * SS + s] = (__bf16)v;
        }
    }
}

// ---------------- final GEMM: out = ctx(hi/lo) @ Wo + bo ----------------
__global__ __launch_bounds__(256, 4) void gemm_out(
    const __bf16* __restrict__ Ahi, const __bf16* __restrict__ Alo,
    const __bf16* __restrict__ Wth, const __bf16* __restrict__ Wtl,
    const float* __restrict__ bias, float* __restrict__ Cf)
{
    const int tid = threadIdx.x;
    const int w = tid >> 6, lane = tid & 63, l15 = lane & 15, lg = lane >> 4;
    const int n0 = blockIdx.x * 64, m0 = blockIdx.y * 64;
    const int mrow = m0 + w * 16 + l15;
    f32x4 acc[4] = {};
    const __bf16* wp = Wth + (size_t)(n0 + l15) * 512 + lg * 8;
    const __bf16* wl = Wtl + (size_t)(n0 + l15) * 512 + lg * 8;

    #pragma unroll 2
    for (int k0 = 0; k0 < 512; k0 += 32) {
        bf16x8 ah = *(const bf16x8*)(Ahi + (size_t)mrow * 512 + k0 + lg * 8);
        bf16x8 al = *(const bf16x8*)(Alo + (size_t)mrow * 512 + k0 + lg * 8);
        #pragma unroll
        for (int nt = 0; nt < 4; ++nt) {
            bf16x8 bh = *(const bf16x8*)(wp + (size_t)nt * 16 * 512 + k0);
            bf16x8 bl = *(const bf16x8*)(wl + (size_t)nt * 16 * 512 + k0);
            acc[nt] = mfma16(ah, bh, acc[nt]);
            acc[nt] = mfma16(al, bh, acc[nt]);
            acc[nt] = mfma16(ah, bl, acc[nt]);
        }
    }
    #pragma unroll
    for (int nt = 0; nt < 4; ++nt) {
        int n = n0 + nt * 16 + l15;
        float bz = bias[n];
        #pragma unroll
        for (int rr = 0; rr < 4; ++rr) {
            int m = m0 + w * 16 + lg * 4 + rr;
            Cf[(size_t)m * 512 + n] = acc[nt][rr] + bz;
        }
    }
}

// ---------------- G precompute: G[b][q][k] = adj*exp(dist+nm-1), rowIL = 1/sum ----
// grid 2048, 256 thr = 4 waves, wave per (b,q)-row.
__global__ __launch_bounds__(256) void gprep(
    const float* __restrict__ mask, const float* __restrict__ adj,
    const float* __restrict__ dist,
    __bf16* __restrict__ Gg, float* __restrict__ rowILg)
{
    const int w = threadIdx.x >> 6, lane = threadIdx.x & 63;
    const int row = blockIdx.x * 4 + w;           // b*1024 + q
    const int b = row >> 10;
    const size_t drow = (size_t)row * SS;
    const float L2E = 1.44269504f;
    const float* mrow = mask + (size_t)b * SS;
    float sm = 0.f;
    #pragma unroll
    for (int j = 0; j < 4; ++j) {
        int c = lane * 4 + j * 256;
        f32x4 d4 = *(const f32x4*)(dist + drow + c);
        f32x4 a4 = *(const f32x4*)(adj + drow + c);
        f32x4 m4 = *(const f32x4*)(mrow + c);
        bf16x4 g4;
        #pragma unroll
        for (int r = 0; r < 4; ++r) {
            float e = exp2f(fmaf(m4[r], -1e9f * L2E, fmaf(d4[r], L2E, -L2E)));
            sm += e;
            g4[r] = (__bf16)(a4[r] * e);
        }
        *(bf16x4*)(Gg + drow + c) = g4;
    }
    #pragma unroll
    for (int off = 1; off <= 32; off <<= 1)
        sm += __shfl_xor(sm, off, 64);
    if (lane == 0) rowILg[row] = 1.0f / sm;
}

// ---------------- Fused attention v5: block = (b, h, 16 q), single QK pass ----------------
// grid 4096 flat: b = bid&7, h = (bid>>3)&7, qt = bid>>6. 256 thr = 4 waves,
// wave w: keys [256w, 256w+256). P~ in LDS [q][key]. One barrier.
__global__ __launch_bounds__(256, 4) void attn5(
    const __bf16* __restrict__ qh, const __bf16* __restrict__ kh,
    const __bf16* __restrict__ vt,
    const float* __restrict__ mask, const __bf16* __restrict__ Gg,
    const float* __restrict__ rowILg,
    float* __restrict__ attn_out, __bf16* __restrict__ chi, __bf16* __restrict__ clo)
{
    __shared__ float nmb[1024];
    __shared__ __align__(16) __bf16 P[16][1032];
    __shared__ float redl[4][16];

    const int tid = threadIdx.x;
    const int w = tid >> 6, lane = tid & 63, l15 = lane & 15, lg = lane >> 4;
    const int bid = blockIdx.x;
    const int b = bid & 7;
    const int h = (bid >> 3) & 7;
    const int q0 = (bid >> 6) * 16;
    const float L2E = 1.44269504f;
    const float c1 = 0.125f * L2E;

    {
        f32x4 m4 = *(const f32x4*)(mask + (size_t)b * SS + tid * 4);
        f32x4 n4;
        #pragma unroll
        for (int r = 0; r < 4; ++r)
            n4[r] = fmaf(m4[r], -1e9f * L2E, -16.0f * L2E);
        *(f32x4*)&nmb[tid * 4] = n4;
    }
    __syncthreads();

    // ---- pass 1: QK^T over this wave's 256 keys; P~ = e*G -> LDS; partial l ----
    const size_t hb = ((size_t)(b * HH + h)) * SS * 64;
    bf16x8 qf[2];
    #pragma unroll
    for (int ks = 0; ks < 2; ++ks)
        qf[ks] = *(const bf16x8*)(qh + hb + (size_t)(q0 + l15) * 64 + ks * 32 + lg * 8);
    const __bf16* kp = kh + hb + (size_t)(w * 256 + l15) * 64 + lg * 8;
    const __bf16* gp = Gg + ((size_t)b * SS + q0 + l15) * SS;

    float lac0 = 0.f, lac1 = 0.f, lac2 = 0.f, lac3 = 0.f;
    bf16x8 ka = *(const bf16x8*)(kp);
    bf16x8 kb2 = *(const bf16x8*)(kp + 32);
    #pragma unroll 4
    for (int nt = 0; nt < 16; ++nt) {
        bf16x8 k0v = ka, k1v = kb2;
        if (nt < 15) {
            ka  = *(const bf16x8*)(kp + (size_t)(nt + 1) * 1024);
            kb2 = *(const bf16x8*)(kp + (size_t)(nt + 1) * 1024 + 32);
        }
        const int kt = w * 16 + nt;
        f32x4 acc = {0.f, 0.f, 0.f, 0.f};
        acc = mfma16(k0v, qf[0], acc);
        acc = mfma16(k1v, qf[1], acc);
        f32x4 nb4 = *(const f32x4*)&nmb[kt * 16 + lg * 4];
        bf16x4 g4 = *(const bf16x4*)(gp + kt * 16 + lg * 4);
        float e0 = exp2f(fmaf(acc[0], c1, nb4[0]));
        float e1 = exp2f(fmaf(acc[1], c1, nb4[1]));
        float e2 = exp2f(fmaf(acc[2], c1, nb4[2]));
        float e3 = exp2f(fmaf(acc[3], c1, nb4[3]));
        lac0 += e0; lac1 += e1; lac2 += e2; lac3 += e3;
        bf16x4 pb;
        pb[0] = (__bf16)(e0 * (float)g4[0]);
        pb[1] = (__bf16)(e1 * (float)g4[1]);
        pb[2] = (__bf16)(e2 * (float)g4[2]);
        pb[3] = (__bf16)(e3 * (float)g4[3]);
        *(bf16x4*)&P[l15][kt * 16 + lg * 4] = pb;
    }
    float l = (lac0 + lac1) + (lac2 + lac3);
    #pragma unroll
    for (int off = 16; off <= 32; off <<= 1)
        l += __shfl_xor(l, off, 64);
    if (lg == 0) redl[w][l15] = l;
    __syncthreads();

    // ---- attn write: wave w -> q-rows [4w, 4w+4) ----
    const float* rg = rowILg + (size_t)b * SS + q0;
    float* aoutb = attn_out + ((size_t)(b * HH + h)) * SS * SS;
    #pragma unroll
    for (int r = 0; r < 4; ++r) {
        const int row = w * 4 + r;
        const float ltot = redl[0][row] + redl[1][row] + redl[2][row] + redl[3][row];
        const float coefR = rg[row] / ltot;
        float* ar = aoutb + (size_t)(q0 + row) * SS;
        #pragma unroll
        for (int j = 0; j < 4; ++j) {
            int c = lane * 4 + j * 256;
            bf16x4 pb = *(const bf16x4*)&P[row][c];
            f32x4 av;
            #pragma unroll
            for (int r2 = 0; r2 < 4; ++r2) av[r2] = (float)pb[r2] * coefR;
            __builtin_nontemporal_store(av, (f32x4*)(ar + c));
        }
    }

    // ---- PV: wave w owns d-cols [16w, 16w+16) over all 1024 keys ----
    f32x4 cacc = {0.f, 0.f, 0.f, 0.f};
    const __bf16* vb = vt + ((size_t)(b * HH + h) * 64 + w * 16 + l15) * SS + lg * 8;
    #pragma unroll 8
    for (int c = 0; c < 32; ++c) {
        bf16x8 pa = *(const bf16x8*)&P[l15][c * 32 + lg * 8];
        cacc = mfma16(pa, *(const bf16x8*)(vb + c * 32), cacc);
    }

    // ---- epilogue: normalize, write ctx hi/lo ----
    #pragma unroll
    for (int r = 0; r < 4; ++r) {
        const int row = lg * 4 + r;
        const float ltot = redl[0][row] + redl[1][row] + redl[2][row] + redl[3][row];
        const float coefE = rg[row] / ltot;
        float x = cacc[r] * coefE;
        __bf16 hv = (__bf16)x;
        size_t idx = ((size_t)b * SS + q0 + row) * DM + h * 64 + w * 16 + l15;
        chi[idx] = hv;
        clo[idx] = (__bf16)(x - (float)hv);
    }
}

extern "C" void kernel_launch(void* const* d_in, const int* in_sizes, int n_in,
                              void* d_out, int out_size, void* d_ws, size_t ws_size,
                              hipStream_t stream) {
    const float* q    = (const float*)d_in[0];
    const float* k    = (const float*)d_in[1];
    const float* v    = (const float*)d_in[2];
    const float* mask = (const float*)d_in[3];
    const float* adj  = (const float*)d_in[4];
    const float* dist = (const float*)d_in[5];
    const float* Wq   = (const float*)d_in[6];
    const float* bq   = (const float*)d_in[7];
    const float* Wk   = (const float*)d_in[8];
    const float* bk   = (const float*)d_in[9];
    const float* Wv   = (const float*)d_in[10];
    const float* bv   = (const float*)d_in[11];
    const float* Wo   = (const float*)d_in[12];
    const float* bo   = (const float*)d_in[13];

    const size_t NT = (size_t)BB * SS * DM;   // 4,194,304
    const size_t WN = 512 * 512;
    const size_t NSS = (size_t)BB * SS * SS;  // 8,388,608
    __bf16* wth = (__bf16*)d_ws;
    __bf16* wtl = wth + 4 * WN;
    __bf16* qhb = wtl + 4 * WN;
    __bf16* khb = qhb + NT;
    __bf16* vtb = khb + NT;
    __bf16* chi = vtb + NT;
    __bf16* clo = chi + NT;
    __bf16* Gg  = clo + NT;
    float* rowILg = (float*)(Gg + NSS);

    float* outp = (float*)d_out;
    float* attn = outp + NT;

    wconv<<<dim3(8, 8, 4), 256, 0, stream>>>(Wq, Wk, Wv, Wo, wth, wtl);

    gprep<<<2048, 256, 0, stream>>>(mask, adj, dist, Gg, rowILg);

    gemm_qkv<<<dim3(24, 128), 256, 0, stream>>>(q, k, v, wth, wtl, bq, bk, bv, qhb, khb, vtb);

    attn5<<<4096, 256, 0, stream>>>(qhb, khb, vtb, mask, Gg, rowILg, attn, chi, clo);

    gemm_out<<<dim3(8, 128), 256, 0, stream>>>(chi, clo, wth + 3 * WN, wtl + 3 * WN, bo, outp);
}

// Round 9
// 253.641 us; speedup vs baseline: 2.2026x; 1.9287x over previous
//
#include <hip/hip_runtime.h>
#include <hip/hip_bf16.h>

#define BB 8
#define SS 1024
#define DM 512
#define HH 8
#define BM 128
#define BN 128
#define BK 32
#define LD 40   // LDS row stride (bf16 elems): 80 B = 16B-aligned, 2-way banks

typedef __bf16 bf16x8 __attribute__((ext_vector_type(8)));
typedef __bf16 bf16x4 __attribute__((ext_vector_type(4)));
typedef float f32x4 __attribute__((ext_vector_type(4)));

__device__ __forceinline__ f32x4 mfma16(bf16x8 a, bf16x8 b, f32x4 c) {
    return __builtin_amdgcn_mfma_f32_16x16x32_bf16(a, b, c, 0, 0, 0);
}

// ---------------- W transpose + hi/lo split ----------------
__global__ __launch_bounds__(256) void wconv(
    const float* __restrict__ W0, const float* __restrict__ W1,
    const float* __restrict__ W2, const float* __restrict__ W3,
    __bf16* __restrict__ th, __bf16* __restrict__ tl)
{
    const float* W = blockIdx.z == 0 ? W0 : blockIdx.z == 1 ? W1
                   : blockIdx.z == 2 ? W2 : W3;
    __bf16* oh = th + (size_t)blockIdx.z * 512 * 512;
    __bf16* ol = tl + (size_t)blockIdx.z * 512 * 512;
    __shared__ float T[64][65];
    const int k0 = blockIdx.x * 64, n0 = blockIdx.y * 64;
    const int r = threadIdx.x >> 4, c4 = (threadIdx.x & 15) * 4;
    #pragma unroll
    for (int p = 0; p < 4; ++p) {
        float4 v = *(const float4*)(W + (size_t)(k0 + p * 16 + r) * 512 + n0 + c4);
        T[p * 16 + r][c4 + 0] = v.x; T[p * 16 + r][c4 + 1] = v.y;
        T[p * 16 + r][c4 + 2] = v.z; T[p * 16 + r][c4 + 3] = v.w;
    }
    __syncthreads();
    #pragma unroll
    for (int p = 0; p < 4; ++p) {
        int n = n0 + p * 16 + r;
        bf16x4 h4, l4;
        #pragma unroll
        for (int j = 0; j < 4; ++j) {
            float x = T[c4 + j][p * 16 + r];
            __bf16 h = (__bf16)x;
            h4[j] = h; l4[j] = (__bf16)(x - (float)h);
        }
        *(bf16x4*)(oh + (size_t)n * 512 + k0 + c4) = h4;
        *(bf16x4*)(ol + (size_t)n * 512 + k0 + c4) = l4;
    }
}

// ---------------- LDS-staged tile GEMM ----------------
// MODE 0: QKV. A fp32 (q/k/v by z = bx>>2), out bf16 head-split (q,k) / transposed (v).
// MODE 1: OUT. A = chi/clo bf16, z=3 weights, fp32 out. bias passed in bq.
// Block: 128m x 128n, BK=32, 256 thr = 4 waves (2x2), wave = 64m x 64n.
template<int MODE>
__global__ __launch_bounds__(256, 3) void gemm_tile(
    const float* __restrict__ Aq, const float* __restrict__ Ak,
    const float* __restrict__ Av,
    const __bf16* __restrict__ Ahig, const __bf16* __restrict__ Alog,
    const __bf16* __restrict__ Wth, const __bf16* __restrict__ Wtl,
    const float* __restrict__ bq, const float* __restrict__ bk,
    const float* __restrict__ bv,
    float* __restrict__ Cf, __bf16* __restrict__ qo, __bf16* __restrict__ ko,
    __bf16* __restrict__ vo)
{
    __shared__ __align__(16) __bf16 Ah[BM][LD];
    __shared__ __align__(16) __bf16 Al[BM][LD];
    __shared__ __align__(16) __bf16 Bh[BN][LD];
    __shared__ __align__(16) __bf16 Bl[BN][LD];

    const int tid = threadIdx.x;
    const int w = tid >> 6, lane = tid & 63, l15 = lane & 15, lg = lane >> 4;
    const int wm = w >> 1, wn = w & 1;
    const int bx = blockIdx.x;
    const int z  = MODE == 0 ? (bx >> 2) : 3;
    const int n0 = MODE == 0 ? (bx & 3) * BN : bx * BN;
    const int m0 = blockIdx.y * BM;

    const float* Afp = (MODE == 0) ? (z == 0 ? Aq : z == 1 ? Ak : Av) : nullptr;
    const __bf16* wh = Wth + (size_t)z * 512 * 512;
    const __bf16* wl = Wtl + (size_t)z * 512 * 512;

    f32x4 acc[4][4];
    #pragma unroll
    for (int i = 0; i < 4; ++i)
        #pragma unroll
        for (int j = 0; j < 4; ++j) acc[i][j] = (f32x4){0.f, 0.f, 0.f, 0.f};

    for (int k0 = 0; k0 < 512; k0 += BK) {
        __syncthreads();
        // ---- stage A ----
        if (MODE == 0) {
            const int row = tid >> 3, c = (tid & 7) * 4;   // 32 rows/pass, 8 thr/row
            #pragma unroll
            for (int p = 0; p < 4; ++p) {
                int rr = row + p * 32;
                f32x4 a = *(const f32x4*)(Afp + (size_t)(m0 + rr) * 512 + k0 + c);
                bf16x4 h4, l4;
                #pragma unroll
                for (int j = 0; j < 4; ++j) {
                    __bf16 h = (__bf16)a[j];
                    h4[j] = h; l4[j] = (__bf16)(a[j] - (float)h);
                }
                *(bf16x4*)&Ah[rr][c] = h4;
                *(bf16x4*)&Al[rr][c] = l4;
            }
        } else {
            const int row = tid >> 2, c = (tid & 3) * 8;   // 64 rows/pass, 4 thr/row
            #pragma unroll
            for (int p = 0; p < 2; ++p) {
                int rr = row + p * 64;
                *(bf16x8*)&Ah[rr][c] =
                    *(const bf16x8*)(Ahig + (size_t)(m0 + rr) * 512 + k0 + c);
                *(bf16x8*)&Al[rr][c] =
                    *(const bf16x8*)(Alog + (size_t)(m0 + rr) * 512 + k0 + c);
            }
        }
        // ---- stage W ----
        {
            const int row = tid >> 2, c = (tid & 3) * 8;
            #pragma unroll
            for (int p = 0; p < 2; ++p) {
                int rr = row + p * 64;
                *(bf16x8*)&Bh[rr][c] =
                    *(const bf16x8*)(wh + (size_t)(n0 + rr) * 512 + k0 + c);
                *(bf16x8*)&Bl[rr][c] =
                    *(const bf16x8*)(wl + (size_t)(n0 + rr) * 512 + k0 + c);
            }
        }
        __syncthreads();

        // ---- compute ----
        bf16x8 afh[4], afl[4];
        #pragma unroll
        for (int mt = 0; mt < 4; ++mt) {
            afh[mt] = *(const bf16x8*)&Ah[wm * 64 + mt * 16 + l15][lg * 8];
            afl[mt] = *(const bf16x8*)&Al[wm * 64 + mt * 16 + l15][lg * 8];
        }
        #pragma unroll
        for (int nt = 0; nt < 4; ++nt) {
            bf16x8 bfh = *(const bf16x8*)&Bh[wn * 64 + nt * 16 + l15][lg * 8];
            bf16x8 bfl = *(const bf16x8*)&Bl[wn * 64 + nt * 16 + l15][lg * 8];
            #pragma unroll
            for (int mt = 0; mt < 4; ++mt) {
                acc[mt][nt] = mfma16(afh[mt], bfh, acc[mt][nt]);
                acc[mt][nt] = mfma16(afl[mt], bfh, acc[mt][nt]);
                acc[mt][nt] = mfma16(afh[mt], bfl, acc[mt][nt]);
            }
        }
    }

    // ---- epilogue ----
    const float* bias = (MODE == 1) ? bq : (z == 0 ? bq : z == 1 ? bk : bv);
    #pragma unroll
    for (int nt = 0; nt < 4; ++nt) {
        const int n = n0 + wn * 64 + nt * 16 + l15;
        const float bz = bias[n];
        #pragma unroll
        for (int mt = 0; mt < 4; ++mt) {
            if (MODE == 0 && z == 2) {
                // V transposed: consecutive rr -> consecutive s
                bf16x4 v4;
                int mbase = m0 + wm * 64 + mt * 16 + lg * 4;
                #pragma unroll
                for (int rr = 0; rr < 4; ++rr)
                    v4[rr] = (__bf16)(acc[mt][nt][rr] + bz);
                int bb = mbase >> 10, s = mbase & 1023, h = n >> 6, d = n & 63;
                *(bf16x4*)(vo + ((size_t)(bb * HH + h) * 64 + d) * SS + s) = v4;
            } else {
                #pragma unroll
                for (int rr = 0; rr < 4; ++rr) {
                    int m = m0 + wm * 64 + mt * 16 + lg * 4 + rr;
                    float v = acc[mt][nt][rr] + bz;
                    if (MODE == 1) {
                        Cf[(size_t)m * 512 + n] = v;
                    } else {
                        int bb = m >> 10, s = m & 1023, h = n >> 6, d = n & 63;
                        __bf16* outp = z == 0 ? qo : ko;
                        outp[((size_t)(bb * HH + h) * SS + s) * 64 + d] = (__bf16)v;
                    }
                }
            }
        }
    }
}

// ---------------- G precompute ----------------
__global__ __launch_bounds__(256) void gprep(
    const float* __restrict__ mask, const float* __restrict__ adj,
    const float* __restrict__ dist,
    __bf16* __restrict__ Gg, float* __restrict__ rowILg)
{
    const int w = threadIdx.x >> 6, lane = threadIdx.x & 63;
    const int row = blockIdx.x * 4 + w;
    const int b = row >> 10;
    const size_t drow = (size_t)row * SS;
    const float L2E = 1.44269504f;
    const float* mrow = mask + (size_t)b * SS;
    float sm = 0.f;
    #pragma unroll
    for (int j = 0; j < 4; ++j) {
        int c = lane * 4 + j * 256;
        f32x4 d4 = *(const f32x4*)(dist + drow + c);
        f32x4 a4 = *(const f32x4*)(adj + drow + c);
        f32x4 m4 = *(const f32x4*)(mrow + c);
        bf16x4 g4;
        #pragma unroll
        for (int r = 0; r < 4; ++r) {
            float e = exp2f(fmaf(m4[r], -1e9f * L2E, fmaf(d4[r], L2E, -L2E)));
            sm += e;
            g4[r] = (__bf16)(a4[r] * e);
        }
        *(bf16x4*)(Gg + drow + c) = g4;
    }
    #pragma unroll
    for (int off = 1; off <= 32; off <<= 1)
        sm += __shfl_xor(sm, off, 64);
    if (lane == 0) rowILg[row] = 1.0f / sm;
}

// ---------------- Fused attention v5 ----------------
__global__ __launch_bounds__(256, 4) void attn5(
    const __bf16* __restrict__ qh, const __bf16* __restrict__ kh,
    const __bf16* __restrict__ vt,
    const float* __restrict__ mask, const __bf16* __restrict__ Gg,
    const float* __restrict__ rowILg,
    float* __restrict__ attn_out, __bf16* __restrict__ chi, __bf16* __restrict__ clo)
{
    __shared__ float nmb[1024];
    __shared__ __align__(16) __bf16 P[16][1032];
    __shared__ float redl[4][16];

    const int tid = threadIdx.x;
    const int w = tid >> 6, lane = tid & 63, l15 = lane & 15, lg = lane >> 4;
    const int bid = blockIdx.x;
    const int b = bid & 7;
    const int h = (bid >> 3) & 7;
    const int q0 = (bid >> 6) * 16;
    const float L2E = 1.44269504f;
    const float c1 = 0.125f * L2E;

    {
        f32x4 m4 = *(const f32x4*)(mask + (size_t)b * SS + tid * 4);
        f32x4 n4;
        #pragma unroll
        for (int r = 0; r < 4; ++r)
            n4[r] = fmaf(m4[r], -1e9f * L2E, -16.0f * L2E);
        *(f32x4*)&nmb[tid * 4] = n4;
    }
    __syncthreads();

    const size_t hb = ((size_t)(b * HH + h)) * SS * 64;
    bf16x8 qf[2];
    #pragma unroll
    for (int ks = 0; ks < 2; ++ks)
        qf[ks] = *(const bf16x8*)(qh + hb + (size_t)(q0 + l15) * 64 + ks * 32 + lg * 8);
    const __bf16* kp = kh + hb + (size_t)(w * 256 + l15) * 64 + lg * 8;
    const __bf16* gp = Gg + ((size_t)b * SS + q0 + l15) * SS;

    float lac0 = 0.f, lac1 = 0.f, lac2 = 0.f, lac3 = 0.f;
    bf16x8 ka = *(const bf16x8*)(kp);
    bf16x8 kb2 = *(const bf16x8*)(kp + 32);
    #pragma unroll 4
    for (int nt = 0; nt < 16; ++nt) {
        bf16x8 k0v = ka, k1v = kb2;
        if (nt < 15) {
            ka  = *(const bf16x8*)(kp + (size_t)(nt + 1) * 1024);
            kb2 = *(const bf16x8*)(kp + (size_t)(nt + 1) * 1024 + 32);
        }
        const int kt = w * 16 + nt;
        f32x4 acc = {0.f, 0.f, 0.f, 0.f};
        acc = mfma16(k0v, qf[0], acc);
        acc = mfma16(k1v, qf[1], acc);
        f32x4 nb4 = *(const f32x4*)&nmb[kt * 16 + lg * 4];
        bf16x4 g4 = *(const bf16x4*)(gp + kt * 16 + lg * 4);
        float e0 = exp2f(fmaf(acc[0], c1, nb4[0]));
        float e1 = exp2f(fmaf(acc[1], c1, nb4[1]));
        float e2 = exp2f(fmaf(acc[2], c1, nb4[2]));
        float e3 = exp2f(fmaf(acc[3], c1, nb4[3]));
        lac0 += e0; lac1 += e1; lac2 += e2; lac3 += e3;
        bf16x4 pb;
        pb[0] = (__bf16)(e0 * (float)g4[0]);
        pb[1] = (__bf16)(e1 * (float)g4[1]);
        pb[2] = (__bf16)(e2 * (float)g4[2]);
        pb[3] = (__bf16)(e3 * (float)g4[3]);
        *(bf16x4*)&P[l15][kt * 16 + lg * 4] = pb;
    }
    float l = (lac0 + lac1) + (lac2 + lac3);
    #pragma unroll
    for (int off = 16; off <= 32; off <<= 1)
        l += __shfl_xor(l, off, 64);
    if (lg == 0) redl[w][l15] = l;
    __syncthreads();

    const float* rg = rowILg + (size_t)b * SS + q0;
    float* aoutb = attn_out + ((size_t)(b * HH + h)) * SS * SS;
    #pragma unroll
    for (int r = 0; r < 4; ++r) {
        const int row = w * 4 + r;
        const float ltot = redl[0][row] + redl[1][row] + redl[2][row] + redl[3][row];
        const float coefR = rg[row] / ltot;
        float* ar = aoutb + (size_t)(q0 + row) * SS;
        #pragma unroll
        for (int j = 0; j < 4; ++j) {
            int c = lane * 4 + j * 256;
            bf16x4 pb = *(const bf16x4*)&P[row][c];
            f32x4 av;
            #pragma unroll
            for (int r2 = 0; r2 < 4; ++r2) av[r2] = (float)pb[r2] * coefR;
            __builtin_nontemporal_store(av, (f32x4*)(ar + c));
        }
    }

    f32x4 cacc = {0.f, 0.f, 0.f, 0.f};
    const __bf16* vb = vt + ((size_t)(b * HH + h) * 64 + w * 16 + l15) * SS + lg * 8;
    #pragma unroll 8
    for (int c = 0; c < 32; ++c) {
        bf16x8 pa = *(const bf16x8*)&P[l15][c * 32 + lg * 8];
        cacc = mfma16(pa, *(const bf16x8*)(vb + c * 32), cacc);
    }

    #pragma unroll
    for (int r = 0; r < 4; ++r) {
        const int row = lg * 4 + r;
        const float ltot = redl[0][row] + redl[1][row] + redl[2][row] + redl[3][row];
        const float coefE = rg[row] / ltot;
        float x = cacc[r] * coefE;
        __bf16 hv = (__bf16)x;
        size_t idx = ((size_t)b * SS + q0 + row) * DM + h * 64 + w * 16 + l15;
        chi[idx] = hv;
        clo[idx] = (__bf16)(x - (float)hv);
    }
}

extern "C" void kernel_launch(void* const* d_in, const int* in_sizes, int n_in,
                              void* d_out, int out_size, void* d_ws, size_t ws_size,
                              hipStream_t stream) {
    const float* q    = (const float*)d_in[0];
    const float* k    = (const float*)d_in[1];
    const float* v    = (const float*)d_in[2];
    const float* mask = (const float*)d_in[3];
    const float* adj  = (const float*)d_in[4];
    const float* dist = (const float*)d_in[5];
    const float* Wq   = (const float*)d_in[6];
    const float* bq   = (const float*)d_in[7];
    const float* Wk   = (const float*)d_in[8];
    const float* bk   = (const float*)d_in[9];
    const float* Wv   = (const float*)d_in[10];
    const float* bv   = (const float*)d_in[11];
    const float* Wo   = (const float*)d_in[12];
    const float* bo   = (const float*)d_in[13];

    const size_t NT = (size_t)BB * SS * DM;   // 4,194,304
    const size_t WN = 512 * 512;
    const size_t NSS = (size_t)BB * SS * SS;  // 8,388,608
    __bf16* wth = (__bf16*)d_ws;
    __bf16* wtl = wth + 4 * WN;
    __bf16* qhb = wtl + 4 * WN;
    __bf16* khb = qhb + NT;
    __bf16* vtb = khb + NT;
    __bf16* chi = vtb + NT;
    __bf16* clo = chi + NT;
    __bf16* Gg  = clo + NT;
    float* rowILg = (float*)(Gg + NSS);

    float* outp = (float*)d_out;
    float* attn = outp + NT;

    wconv<<<dim3(8, 8, 4), 256, 0, stream>>>(Wq, Wk, Wv, Wo, wth, wtl);

    gprep<<<2048, 256, 0, stream>>>(mask, adj, dist, Gg, rowILg);

    gemm_tile<0><<<dim3(12, 64), 256, 0, stream>>>(
        q, k, v, nullptr, nullptr, wth, wtl, bq, bk, bv,
        nullptr, qhb, khb, vtb);

    attn5<<<4096, 256, 0, stream>>>(qhb, khb, vtb, mask, Gg, rowILg, attn, chi, clo);

    gemm_tile<1><<<dim3(4, 64), 256, 0, stream>>>(
        nullptr, nullptr, nullptr, chi, clo, wth, wtl, bo, nullptr, nullptr,
        outp, nullptr, nullptr, nullptr);
}

// Round 10
// 243.450 us; speedup vs baseline: 2.2948x; 1.0419x over previous
//
#include <hip/hip_runtime.h>
#include <hip/hip_bf16.h>

#define BB 8
#define SS 1024
#define DM 512
#define HH 8
#define BM 128
#define BN 128
#define BK 32
#define LD 40   // LDS row stride (bf16 elems): 80 B = 16B-aligned, 2-way banks

typedef __bf16 bf16x8 __attribute__((ext_vector_type(8)));
typedef __bf16 bf16x4 __attribute__((ext_vector_type(4)));
typedef float f32x4 __attribute__((ext_vector_type(4)));

__device__ __forceinline__ f32x4 mfma16(bf16x8 a, bf16x8 b, f32x4 c) {
    return __builtin_amdgcn_mfma_f32_16x16x32_bf16(a, b, c, 0, 0, 0);
}

// ---------------- W transpose + hi/lo split ----------------
__global__ __launch_bounds__(256) void wconv(
    const float* __restrict__ W0, const float* __restrict__ W1,
    const float* __restrict__ W2, const float* __restrict__ W3,
    __bf16* __restrict__ th, __bf16* __restrict__ tl)
{
    const float* W = blockIdx.z == 0 ? W0 : blockIdx.z == 1 ? W1
                   : blockIdx.z == 2 ? W2 : W3;
    __bf16* oh = th + (size_t)blockIdx.z * 512 * 512;
    __bf16* ol = tl + (size_t)blockIdx.z * 512 * 512;
    __shared__ float T[64][65];
    const int k0 = blockIdx.x * 64, n0 = blockIdx.y * 64;
    const int r = threadIdx.x >> 4, c4 = (threadIdx.x & 15) * 4;
    #pragma unroll
    for (int p = 0; p < 4; ++p) {
        float4 v = *(const float4*)(W + (size_t)(k0 + p * 16 + r) * 512 + n0 + c4);
        T[p * 16 + r][c4 + 0] = v.x; T[p * 16 + r][c4 + 1] = v.y;
        T[p * 16 + r][c4 + 2] = v.z; T[p * 16 + r][c4 + 3] = v.w;
    }
    __syncthreads();
    #pragma unroll
    for (int p = 0; p < 4; ++p) {
        int n = n0 + p * 16 + r;
        bf16x4 h4, l4;
        #pragma unroll
        for (int j = 0; j < 4; ++j) {
            float x = T[c4 + j][p * 16 + r];
            __bf16 h = (__bf16)x;
            h4[j] = h; l4[j] = (__bf16)(x - (float)h);
        }
        *(bf16x4*)(oh + (size_t)n * 512 + k0 + c4) = h4;
        *(bf16x4*)(ol + (size_t)n * 512 + k0 + c4) = l4;
    }
}

// ---------------- LDS-staged tile GEMM ----------------
// MODE 0: QKV. A fp32 -> single bf16 (2-MFMA vs W hi/lo), out bf16 head-split / V^T.
// MODE 1: OUT. A = chi/clo bf16 (3-MFMA), z=3 weights, fp32 out. bias in bq.
template<int MODE>
__global__ __launch_bounds__(256, 3) void gemm_tile(
    const float* __restrict__ Aq, const float* __restrict__ Ak,
    const float* __restrict__ Av,
    const __bf16* __restrict__ Ahig, const __bf16* __restrict__ Alog,
    const __bf16* __restrict__ Wth, const __bf16* __restrict__ Wtl,
    const float* __restrict__ bq, const float* __restrict__ bk,
    const float* __restrict__ bv,
    float* __restrict__ Cf, __bf16* __restrict__ qo, __bf16* __restrict__ ko,
    __bf16* __restrict__ vo)
{
    __shared__ __align__(16) __bf16 Ah[BM][LD];
    __shared__ __align__(16) __bf16 Al[(MODE == 1 ? BM : 1)][LD];
    __shared__ __align__(16) __bf16 Bh[BN][LD];
    __shared__ __align__(16) __bf16 Bl[BN][LD];

    const int tid = threadIdx.x;
    const int w = tid >> 6, lane = tid & 63, l15 = lane & 15, lg = lane >> 4;
    const int wm = w >> 1, wn = w & 1;
    const int bx = blockIdx.x;
    const int z  = MODE == 0 ? (bx >> 2) : 3;
    const int n0 = MODE == 0 ? (bx & 3) * BN : bx * BN;
    const int m0 = blockIdx.y * BM;

    const float* Afp = (MODE == 0) ? (z == 0 ? Aq : z == 1 ? Ak : Av) : nullptr;
    const __bf16* wh = Wth + (size_t)z * 512 * 512;
    const __bf16* wl = Wtl + (size_t)z * 512 * 512;

    f32x4 acc[4][4];
    #pragma unroll
    for (int i = 0; i < 4; ++i)
        #pragma unroll
        for (int j = 0; j < 4; ++j) acc[i][j] = (f32x4){0.f, 0.f, 0.f, 0.f};

    for (int k0 = 0; k0 < 512; k0 += BK) {
        __syncthreads();
        if (MODE == 0) {
            const int row = tid >> 3, c = (tid & 7) * 4;
            #pragma unroll
            for (int p = 0; p < 4; ++p) {
                int rr = row + p * 32;
                f32x4 a = *(const f32x4*)(Afp + (size_t)(m0 + rr) * 512 + k0 + c);
                bf16x4 h4;
                #pragma unroll
                for (int j = 0; j < 4; ++j) h4[j] = (__bf16)a[j];
                *(bf16x4*)&Ah[rr][c] = h4;
            }
        } else {
            const int row = tid >> 2, c = (tid & 3) * 8;
            #pragma unroll
            for (int p = 0; p < 2; ++p) {
                int rr = row + p * 64;
                *(bf16x8*)&Ah[rr][c] =
                    *(const bf16x8*)(Ahig + (size_t)(m0 + rr) * 512 + k0 + c);
                *(bf16x8*)&Al[rr][c] =
                    *(const bf16x8*)(Alog + (size_t)(m0 + rr) * 512 + k0 + c);
            }
        }
        {
            const int row = tid >> 2, c = (tid & 3) * 8;
            #pragma unroll
            for (int p = 0; p < 2; ++p) {
                int rr = row + p * 64;
                *(bf16x8*)&Bh[rr][c] =
                    *(const bf16x8*)(wh + (size_t)(n0 + rr) * 512 + k0 + c);
                *(bf16x8*)&Bl[rr][c] =
                    *(const bf16x8*)(wl + (size_t)(n0 + rr) * 512 + k0 + c);
            }
        }
        __syncthreads();

        bf16x8 afh[4], afl[4];
        #pragma unroll
        for (int mt = 0; mt < 4; ++mt) {
            afh[mt] = *(const bf16x8*)&Ah[wm * 64 + mt * 16 + l15][lg * 8];
            if (MODE == 1)
                afl[mt] = *(const bf16x8*)&Al[wm * 64 + mt * 16 + l15][lg * 8];
        }
        #pragma unroll
        for (int nt = 0; nt < 4; ++nt) {
            bf16x8 bfh = *(const bf16x8*)&Bh[wn * 64 + nt * 16 + l15][lg * 8];
            bf16x8 bfl = *(const bf16x8*)&Bl[wn * 64 + nt * 16 + l15][lg * 8];
            #pragma unroll
            for (int mt = 0; mt < 4; ++mt) {
                acc[mt][nt] = mfma16(afh[mt], bfh, acc[mt][nt]);
                acc[mt][nt] = mfma16(afh[mt], bfl, acc[mt][nt]);
                if (MODE == 1)
                    acc[mt][nt] = mfma16(afl[mt], bfh, acc[mt][nt]);
            }
        }
    }

    const float* bias = (MODE == 1) ? bq : (z == 0 ? bq : z == 1 ? bk : bv);
    #pragma unroll
    for (int nt = 0; nt < 4; ++nt) {
        const int n = n0 + wn * 64 + nt * 16 + l15;
        const float bz = bias[n];
        #pragma unroll
        for (int mt = 0; mt < 4; ++mt) {
            if (MODE == 0 && z == 2) {
                bf16x4 v4;
                int mbase = m0 + wm * 64 + mt * 16 + lg * 4;
                #pragma unroll
                for (int rr = 0; rr < 4; ++rr)
                    v4[rr] = (__bf16)(acc[mt][nt][rr] + bz);
                int bb = mbase >> 10, s = mbase & 1023, h = n >> 6, d = n & 63;
                *(bf16x4*)(vo + ((size_t)(bb * HH + h) * 64 + d) * SS + s) = v4;
            } else {
                #pragma unroll
                for (int rr = 0; rr < 4; ++rr) {
                    int m = m0 + wm * 64 + mt * 16 + lg * 4 + rr;
                    float v = acc[mt][nt][rr] + bz;
                    if (MODE == 1) {
                        Cf[(size_t)m * 512 + n] = v;
                    } else {
                        int bb = m >> 10, s = m & 1023, h = n >> 6, d = n & 63;
                        __bf16* outp = z == 0 ? qo : ko;
                        outp[((size_t)(bb * HH + h) * SS + s) * 64 + d] = (__bf16)v;
                    }
                }
            }
        }
    }
}

// ---------------- G precompute ----------------
__global__ __launch_bounds__(256) void gprep(
    const float* __restrict__ mask, const float* __restrict__ adj,
    const float* __restrict__ dist,
    __bf16* __restrict__ Gg, float* __restrict__ rowILg)
{
    const int w = threadIdx.x >> 6, lane = threadIdx.x & 63;
    const int row = blockIdx.x * 4 + w;
    const int b = row >> 10;
    const size_t drow = (size_t)row * SS;
    const float L2E = 1.44269504f;
    const float* mrow = mask + (size_t)b * SS;
    float sm = 0.f;
    #pragma unroll
    for (int j = 0; j < 4; ++j) {
        int c = lane * 4 + j * 256;
        f32x4 d4 = *(const f32x4*)(dist + drow + c);
        f32x4 a4 = *(const f32x4*)(adj + drow + c);
        f32x4 m4 = *(const f32x4*)(mrow + c);
        bf16x4 g4;
        #pragma unroll
        for (int r = 0; r < 4; ++r) {
            float e = exp2f(fmaf(m4[r], -1e9f * L2E, fmaf(d4[r], L2E, -L2E)));
            sm += e;
            g4[r] = (__bf16)(a4[r] * e);
        }
        *(bf16x4*)(Gg + drow + c) = g4;
    }
    #pragma unroll
    for (int off = 1; off <= 32; off <<= 1)
        sm += __shfl_xor(sm, off, 64);
    if (lane == 0) rowILg[row] = 1.0f / sm;
}

// ---------------- Fused attention v6: swizzled P, depth-4 prefetch ----------------
__global__ __launch_bounds__(256, 4) void attn6(
    const __bf16* __restrict__ qh, const __bf16* __restrict__ kh,
    const __bf16* __restrict__ vt,
    const float* __restrict__ mask, const __bf16* __restrict__ Gg,
    const float* __restrict__ rowILg,
    float* __restrict__ attn_out, __bf16* __restrict__ chi, __bf16* __restrict__ clo)
{
    __shared__ float nmb[1024];
    __shared__ __align__(16) __bf16 P[16][1024];   // XOR-swizzled: byte ^= (row&7)<<4
    __shared__ float redl[4][16];

    const int tid = threadIdx.x;
    const int w = tid >> 6, lane = tid & 63, l15 = lane & 15, lg = lane >> 4;
    const int bid = blockIdx.x;
    const int b = bid & 7;
    const int h = (bid >> 3) & 7;
    const int q0 = (bid >> 6) * 16;
    const float L2E = 1.44269504f;
    const float c1 = 0.125f * L2E;

    char* Pb = (char*)P;
    #define PADDR(row, bytes) (Pb + (row) * 2048 + ((bytes) ^ (((row) & 7) << 4)))

    {
        f32x4 m4 = *(const f32x4*)(mask + (size_t)b * SS + tid * 4);
        f32x4 n4;
        #pragma unroll
        for (int r = 0; r < 4; ++r)
            n4[r] = fmaf(m4[r], -1e9f * L2E, -16.0f * L2E);
        *(f32x4*)&nmb[tid * 4] = n4;
    }
    __syncthreads();

    const size_t hb = ((size_t)(b * HH + h)) * SS * 64;
    bf16x8 qf[2];
    #pragma unroll
    for (int ks = 0; ks < 2; ++ks)
        qf[ks] = *(const bf16x8*)(qh + hb + (size_t)(q0 + l15) * 64 + ks * 32 + lg * 8);
    const __bf16* kp = kh + hb + (size_t)(w * 256 + l15) * 64 + lg * 8;
    const __bf16* gp = Gg + ((size_t)b * SS + q0 + l15) * SS;

    // ---- pass 1: QK^T over this wave's 256 keys, depth-4 K/G pipeline ----
    float lac0 = 0.f, lac1 = 0.f, lac2 = 0.f, lac3 = 0.f;
    bf16x8 ks0[4], ks1[4];
    bf16x4 gs[4];
    #pragma unroll
    for (int i = 0; i < 4; ++i) {
        ks0[i] = *(const bf16x8*)(kp + (size_t)i * 1024);
        ks1[i] = *(const bf16x8*)(kp + (size_t)i * 1024 + 32);
        gs[i]  = *(const bf16x4*)(gp + (w * 16 + i) * 16 + lg * 4);
    }
    #pragma unroll
    for (int nt = 0; nt < 16; ++nt) {
        const int sl = nt & 3;
        bf16x8 k0v = ks0[sl], k1v = ks1[sl];
        bf16x4 g4 = gs[sl];
        if (nt + 4 < 16) {
            ks0[sl] = *(const bf16x8*)(kp + (size_t)(nt + 4) * 1024);
            ks1[sl] = *(const bf16x8*)(kp + (size_t)(nt + 4) * 1024 + 32);
            gs[sl]  = *(const bf16x4*)(gp + (w * 16 + nt + 4) * 16 + lg * 4);
        }
        const int kt = w * 16 + nt;
        f32x4 acc = {0.f, 0.f, 0.f, 0.f};
        acc = mfma16(k0v, qf[0], acc);
        acc = mfma16(k1v, qf[1], acc);
        f32x4 nb4 = *(const f32x4*)&nmb[kt * 16 + lg * 4];
        float e0 = exp2f(fmaf(acc[0], c1, nb4[0]));
        float e1 = exp2f(fmaf(acc[1], c1, nb4[1]));
        float e2 = exp2f(fmaf(acc[2], c1, nb4[2]));
        float e3 = exp2f(fmaf(acc[3], c1, nb4[3]));
        lac0 += e0; lac1 += e1; lac2 += e2; lac3 += e3;
        bf16x4 pb;
        pb[0] = (__bf16)(e0 * (float)g4[0]);
        pb[1] = (__bf16)(e1 * (float)g4[1]);
        pb[2] = (__bf16)(e2 * (float)g4[2]);
        pb[3] = (__bf16)(e3 * (float)g4[3]);
        *(bf16x4*)PADDR(l15, kt * 32 + lg * 8) = pb;
    }
    float l = (lac0 + lac1) + (lac2 + lac3);
    #pragma unroll
    for (int off = 16; off <= 32; off <<= 1)
        l += __shfl_xor(l, off, 64);
    if (lg == 0) redl[w][l15] = l;
    __syncthreads();

    // ---- attn write: wave w -> q-rows [4w, 4w+4) ----
    const float* rg = rowILg + (size_t)b * SS + q0;
    float* aoutb = attn_out + ((size_t)(b * HH + h)) * SS * SS;
    #pragma unroll
    for (int r = 0; r < 4; ++r) {
        const int row = w * 4 + r;
        const float ltot = redl[0][row] + redl[1][row] + redl[2][row] + redl[3][row];
        const float coefR = rg[row] / ltot;
        float* ar = aoutb + (size_t)(q0 + row) * SS;
        #pragma unroll
        for (int j = 0; j < 4; ++j) {
            bf16x4 pb = *(const bf16x4*)PADDR(row, lane * 8 + j * 512);
            f32x4 av;
            #pragma unroll
            for (int r2 = 0; r2 < 4; ++r2) av[r2] = (float)pb[r2] * coefR;
            __builtin_nontemporal_store(av, (f32x4*)(ar + ((lane * 8 + j * 512) >> 1)));
        }
    }

    // ---- PV: wave w owns d-cols [16w,16w+16), depth-4 V pipeline ----
    f32x4 cacc = {0.f, 0.f, 0.f, 0.f};
    const __bf16* vb = vt + ((size_t)(b * HH + h) * 64 + w * 16 + l15) * SS + lg * 8;
    bf16x8 vs[4];
    #pragma unroll
    for (int i = 0; i < 4; ++i) vs[i] = *(const bf16x8*)(vb + i * 32);
    #pragma unroll
    for (int c = 0; c < 32; ++c) {
        const int sl = c & 3;
        bf16x8 vv = vs[sl];
        if (c + 4 < 32) vs[sl] = *(const bf16x8*)(vb + (c + 4) * 32);
        bf16x8 pa = *(const bf16x8*)PADDR(l15, c * 64 + lg * 16);
        cacc = mfma16(pa, vv, cacc);
    }

    // ---- epilogue ----
    #pragma unroll
    for (int r = 0; r < 4; ++r) {
        const int row = lg * 4 + r;
        const float ltot = redl[0][row] + redl[1][row] + redl[2][row] + redl[3][row];
        const float coefE = rg[row] / ltot;
        float x = cacc[r] * coefE;
        __bf16 hv = (__bf16)x;
        size_t idx = ((size_t)b * SS + q0 + row) * DM + h * 64 + w * 16 + l15;
        chi[idx] = hv;
        clo[idx] = (__bf16)(x - (float)hv);
    }
    #undef PADDR
}

extern "C" void kernel_launch(void* const* d_in, const int* in_sizes, int n_in,
                              void* d_out, int out_size, void* d_ws, size_t ws_size,
                              hipStream_t stream) {
    const float* q    = (const float*)d_in[0];
    const float* k    = (const float*)d_in[1];
    const float* v    = (const float*)d_in[2];
    const float* mask = (const float*)d_in[3];
    const float* adj  = (const float*)d_in[4];
    const float* dist = (const float*)d_in[5];
    const float* Wq   = (const float*)d_in[6];
    const float* bq   = (const float*)d_in[7];
    const float* Wk   = (const float*)d_in[8];
    const float* bk   = (const float*)d_in[9];
    const float* Wv   = (const float*)d_in[10];
    const float* bv   = (const float*)d_in[11];
    const float* Wo   = (const float*)d_in[12];
    const float* bo   = (const float*)d_in[13];

    const size_t NT = (size_t)BB * SS * DM;   // 4,194,304
    const size_t WN = 512 * 512;
    const size_t NSS = (size_t)BB * SS * SS;  // 8,388,608
    __bf16* wth = (__bf16*)d_ws;
    __bf16* wtl = wth + 4 * WN;
    __bf16* qhb = wtl + 4 * WN;
    __bf16* khb = qhb + NT;
    __bf16* vtb = khb + NT;
    __bf16* chi = vtb + NT;
    __bf16* clo = chi + NT;
    __bf16* Gg  = clo + NT;
    float* rowILg = (float*)(Gg + NSS);

    float* outp = (float*)d_out;
    float* attn = outp + NT;

    wconv<<<dim3(8, 8, 4), 256, 0, stream>>>(Wq, Wk, Wv, Wo, wth, wtl);

    gprep<<<2048, 256, 0, stream>>>(mask, adj, dist, Gg, rowILg);

    gemm_tile<0><<<dim3(12, 64), 256, 0, stream>>>(
        q, k, v, nullptr, nullptr, wth, wtl, bq, bk, bv,
        nullptr, qhb, khb, vtb);

    attn6<<<4096, 256, 0, stream>>>(qhb, khb, vtb, mask, Gg, rowILg, attn, chi, clo);

    gemm_tile<1><<<dim3(4, 64), 256, 0, stream>>>(
        nullptr, nullptr, nullptr, chi, clo, wth, wtl, bo, nullptr, nullptr,
        outp, nullptr, nullptr, nullptr);
}